// Round 9
// baseline (573.830 us; speedup 1.0000x reference)
//
#include <hip/hip_runtime.h>
#include <math.h>

#define HIDDEN 1024
#define INTER 4096
#define NE 8

typedef __bf16 bf16;
typedef __bf16 bf16x8 __attribute__((ext_vector_type(8)));
typedef float f32x4 __attribute__((ext_vector_type(4)));

// ---- workspace layout (bytes) ----
#define WS_CTRL   ((size_t)0)
#define WS_PERM   ((size_t)256)
#define WS_GATES  ((size_t)65792)
#define WS_EIDX   ((size_t)131328)
#define WS_EGATE  ((size_t)196864)
#define WS_XB     ((size_t)262400)
#define WS_UPWB   ((size_t)17039616)
#define WS_DOWNWB ((size_t)84148480)
#define WS_H      ((size_t)151257344)
#define WS_T2S    ((size_t)285475072)
#define WS_Y      WS_UPWB   // y overlays upwb (dead after up_gemm)

__device__ __forceinline__ void async_copy16(const void* g, void* l) {
  __builtin_amdgcn_global_load_lds((const __attribute__((address_space(1))) void*)g,
                                   (__attribute__((address_space(3))) void*)l, 16, 0, 0);
}

// bijective XCD chunk remap (m204)
__device__ __forceinline__ int xcd_remap(int orig, int nwg) {
  int q = nwg >> 3, r = nwg & 7;
  int xcd = orig & 7, idx = orig >> 3;
  int base = (xcd < r) ? xcd * (q + 1) : r * (q + 1) + (xcd - r) * q;
  return base + idx;
}

// exact-erf GELU via Abramowitz-Stegun 7.1.26 (abs err 1.5e-7)
__device__ __forceinline__ float gelu_erf(float v) {
  float x = v * 0.70710678118654752440f;
  float ax = fabsf(x);
  float t = __builtin_amdgcn_rcpf(fmaf(0.3275911f, ax, 1.0f));
  float p = fmaf(t, 1.061405429f, -1.453152027f);
  p = fmaf(p, t, 1.421413741f);
  p = fmaf(p, t, -0.284496736f);
  p = fmaf(p, t, 0.254829592f);
  p = p * t;
  float e = __expf(-x * x);
  float er = 1.0f - p * e;
  er = copysignf(er, x);
  return 0.5f * v * (1.0f + er);
}

// ---------------- weight fp32 -> bf16 convert ----------------
__global__ void cvt_kernel(const float* __restrict__ w, bf16* __restrict__ wb, int n4) {
  int i = blockIdx.x * blockDim.x + threadIdx.x;
  int stride = gridDim.x * blockDim.x;
  for (; i < n4; i += stride) {
    float4 v = ((const float4*)w)[i];
    union { bf16 b[4]; uint2 u; } cv;
    cv.b[0] = (bf16)v.x; cv.b[1] = (bf16)v.y; cv.b[2] = (bf16)v.z; cv.b[3] = (bf16)v.w;
    ((uint2*)wb)[i] = cv.u;
  }
}

// ---------------- router: LN + logits + top2 + xb emit ----------------
__global__ __launch_bounds__(256)
void router_kernel(const float* __restrict__ x, const float* __restrict__ lns,
                   const float* __restrict__ lnb, const float* __restrict__ rw,
                   const float* __restrict__ rb, bf16* __restrict__ xb,
                   int* __restrict__ eidx, float* __restrict__ egate) {
  const int lane = threadIdx.x & 63;
  const int wid = threadIdx.x >> 6;
  const int t = blockIdx.x * 4 + wid;
  const float4* xr = (const float4*)(x + (size_t)t * HIDDEN);
  float4 v[4];
  float s = 0.f, ss = 0.f;
#pragma unroll
  for (int q = 0; q < 4; ++q) {
    v[q] = xr[q * 64 + lane];
    s += v[q].x + v[q].y + v[q].z + v[q].w;
    ss += v[q].x * v[q].x + v[q].y * v[q].y + v[q].z * v[q].z + v[q].w * v[q].w;
  }
#pragma unroll
  for (int o = 32; o; o >>= 1) { s += __shfl_xor(s, o, 64); ss += __shfl_xor(ss, o, 64); }
  const float mu = s * (1.f / HIDDEN);
  const float rstd = rsqrtf(ss * (1.f / HIDDEN) - mu * mu + 1e-5f);
  float acc[NE] = {};
#pragma unroll
  for (int q = 0; q < 4; ++q) {
    int i4 = q * 64 + lane;
    float4 xv = v[q];
    float4 sc = ((const float4*)lns)[i4];
    float4 bi = ((const float4*)lnb)[i4];
    float4 xn;
    xn.x = (xv.x - mu) * rstd * sc.x + bi.x;
    xn.y = (xv.y - mu) * rstd * sc.y + bi.y;
    xn.z = (xv.z - mu) * rstd * sc.z + bi.z;
    xn.w = (xv.w - mu) * rstd * sc.w + bi.w;
#pragma unroll
    for (int e2 = 0; e2 < NE; ++e2) {
      float4 w = ((const float4*)(rw + e2 * HIDDEN))[i4];
      acc[e2] += xn.x * w.x + xn.y * w.y + xn.z * w.z + xn.w * w.w;
    }
    union { bf16 b[4]; uint2 u; } cv;
    cv.b[0] = (bf16)xv.x; cv.b[1] = (bf16)xv.y; cv.b[2] = (bf16)xv.z; cv.b[3] = (bf16)xv.w;
    *(uint2*)&xb[(size_t)t * HIDDEN + i4 * 4] = cv.u;
  }
#pragma unroll
  for (int e2 = 0; e2 < NE; ++e2)
#pragma unroll
    for (int o = 32; o; o >>= 1) acc[e2] += __shfl_xor(acc[e2], o, 64);
  if (lane == 0) {
    float b0 = -1e30f, b1 = -1e30f; int i0 = 0, i1 = 0;
#pragma unroll
    for (int e2 = 0; e2 < NE; ++e2) {
      float lv = acc[e2] + rb[e2];
      if (lv > b0) { b1 = b0; i1 = i0; b0 = lv; i0 = e2; }
      else if (lv > b1) { b1 = lv; i1 = e2; }
    }
    float ex = expf(b1 - b0);
    float g0 = 1.f / (1.f + ex);
    float g1 = ex * g0;
    eidx[t * 2] = i0; eidx[t * 2 + 1] = i1;
    egate[t * 2] = g0; egate[t * 2 + 1] = g1;
  }
}

// ---------------- histogram ----------------
__global__ __launch_bounds__(256)
void hist_kernel(const int* __restrict__ eidx, int* __restrict__ cnt) {
  __shared__ int h8[NE];
  if (threadIdx.x < NE) h8[threadIdx.x] = 0;
  __syncthreads();
  int i = (blockIdx.x * 256 + threadIdx.x) * 4;
#pragma unroll
  for (int k = 0; k < 4; ++k) atomicAdd(&h8[eidx[i + k]], 1);
  __syncthreads();
  if (threadIdx.x < NE) atomicAdd(&cnt[threadIdx.x], h8[threadIdx.x]);
}

__global__ void scan_kernel(const int* cnt, int* offs) {
  if (threadIdx.x == 0 && blockIdx.x == 0) {
    int a = 0;
    for (int e = 0; e < NE; ++e) { offs[e] = a; a += cnt[e]; }
    offs[NE] = a;
  }
}

// ---------------- scatter ----------------
__global__ __launch_bounds__(256)
void scatter_kernel(const int* __restrict__ eidx, const float* __restrict__ egate,
                    const int* __restrict__ offs, int* __restrict__ fill,
                    int* __restrict__ perm, float* __restrict__ gates,
                    int* __restrict__ t2s) {
  __shared__ int h8[NE], base8[NE];
  if (threadIdx.x < NE) h8[threadIdx.x] = 0;
  __syncthreads();
  int i = (blockIdx.x * 256 + threadIdx.x) * 4;
  int ee[4], rk[4];
#pragma unroll
  for (int k = 0; k < 4; ++k) { ee[k] = eidx[i + k]; rk[k] = atomicAdd(&h8[ee[k]], 1); }
  __syncthreads();
  if (threadIdx.x < NE) base8[threadIdx.x] = atomicAdd(&fill[threadIdx.x], h8[threadIdx.x]);
  __syncthreads();
#pragma unroll
  for (int k = 0; k < 4; ++k) {
    int entry = i + k;
    int slot = offs[ee[k]] + base8[ee[k]] + rk[k];
    perm[slot] = entry >> 1;
    gates[slot] = egate[entry];
    t2s[entry] = slot;
  }
}

// ---------------- shared 8-phase 256x256 GEMM machinery (R6 schedule) ----------------
//   A half h: rows {h*64..+63} U {128+h*64..+63}    B half h: rows {h*32+q*64..+31}
#define READ_A(hh, cb) { \
  _Pragma("unroll") for (int ii = 0; ii < 4; ++ii) \
  _Pragma("unroll") for (int ks = 0; ks < 2; ++ks) { \
    int r_ = wr * 128 + (hh) * 64 + ii * 16 + l15; \
    af[ii][ks] = *(const bf16x8*)&sA[cb][r_ * 64 + (((ks * 4 + l16) ^ (r_ & 7)) * 8)]; \
  } }

#define READ_B(jh, cb) { \
  _Pragma("unroll") for (int jj = 0; jj < 2; ++jj) \
  _Pragma("unroll") for (int ks = 0; ks < 2; ++ks) { \
    int n_ = wc * 64 + ((jh) * 2 + jj) * 16 + l15; \
    bfr[jh][jj][ks] = *(const bf16x8*)&sB[cb][n_ * 64 + (((ks * 4 + l16) ^ (n_ & 7)) * 8)]; \
  } }

#define STAGE_A(ha, nb) { \
  async_copy16(ga[ha][0], &sA[nb][la[ha][0]]); \
  async_copy16(ga[ha][1], &sA[nb][la[ha][1]]); \
  ga[ha][0] += 64; ga[ha][1] += 64; }

#define STAGE_B(hb, nb) { \
  async_copy16(gb[hb][0], &sB[nb][lb[hb][0]]); \
  async_copy16(gb[hb][1], &sB[nb][lb[hb][1]]); \
  gb[hb][0] += 64; gb[hb][1] += 64; }

#define MFMA_CLUSTER(I0, JH) \
  __builtin_amdgcn_s_barrier(); \
  asm volatile("s_waitcnt lgkmcnt(0)" ::: "memory"); \
  __builtin_amdgcn_sched_barrier(0); \
  __builtin_amdgcn_s_setprio(1); \
  { _Pragma("unroll") for (int ii = 0; ii < 4; ++ii) \
    _Pragma("unroll") for (int jj = 0; jj < 2; ++jj) \
    _Pragma("unroll") for (int ks = 0; ks < 2; ++ks) \
      acc[(I0) + ii][(JH) * 2 + jj] = __builtin_amdgcn_mfma_f32_16x16x32_bf16( \
          af[ii][ks], bfr[JH][jj][ks], acc[(I0) + ii][(JH) * 2 + jj], 0, 0, 0); } \
  __builtin_amdgcn_s_setprio(0); \
  __builtin_amdgcn_sched_barrier(0); \
  __builtin_amdgcn_s_barrier();

#define VMW(n) asm volatile("s_waitcnt vmcnt(" #n ")" ::: "memory");

#define GEMM8_MAIN_LOOP(NT) \
  STAGE_A(0, 0); STAGE_B(0, 0); STAGE_B(1, 0); STAGE_A(1, 0); \
  VMW(4); \
  __builtin_amdgcn_s_barrier(); \
  for (int t = 0; t < (NT) - 1; ++t) { \
    const int cb = t & 1, nb = cb ^ 1; \
    READ_A(0, cb); READ_B(0, cb); \
    STAGE_A(0, nb); \
    VMW(4); \
    MFMA_CLUSTER(0, 0); \
    READ_B(1, cb); \
    STAGE_B(0, nb); \
    VMW(4); \
    MFMA_CLUSTER(0, 1); \
    READ_A(1, cb); \
    STAGE_B(1, nb); \
    MFMA_CLUSTER(4, 1); \
    STAGE_A(1, nb); \
    VMW(4); \
    MFMA_CLUSTER(4, 0); \
  } \
  { \
    const int cb = ((NT) - 1) & 1; \
    READ_A(0, cb); READ_B(0, cb); \
    VMW(0); \
    MFMA_CLUSTER(0, 0); \
    READ_B(1, cb); \
    MFMA_CLUSTER(0, 1); \
    READ_A(1, cb); \
    MFMA_CLUSTER(4, 1); \
    MFMA_CLUSTER(4, 0); \
  }

// ---------------- 8-phase 256x256 grouped up GEMM (XCD-chunked, rt-inner) ----------------
#define UP_CT (INTER / 256)   // 16
#define UP_RT 32
__global__ __launch_bounds__(512, 2)
void up_gemm8(const bf16* __restrict__ xb, const bf16* __restrict__ wb,
              const float* __restrict__ upb, const int* __restrict__ perm,
              const int* __restrict__ offs, bf16* __restrict__ h) {
  const int wgid = xcd_remap(blockIdx.x, UP_CT * UP_RT * NE);
  // rt-inner within expert chunk: concurrent blocks share few B panels (L2-fit)
  const int rt = wgid % UP_RT;
  const int ct = (wgid / UP_RT) % UP_CT;
  const int e  = wgid / (UP_CT * UP_RT);
  const int pbase = offs[e];
  const int ne = offs[e + 1] - pbase;
  if (rt * 256 >= ne) return;
  __shared__ __align__(16) bf16 sMem[4][256 * 64];   // sA = [0..1], sB = [2..3]
  bf16 (* const sA)[256 * 64] = sMem;
  bf16 (* const sB)[256 * 64] = sMem + 2;
  const int tid = threadIdx.x;
  const int lane = tid & 63;
  const int wid = tid >> 6;
  const int wr = wid >> 2;
  const int wc = wid & 3;
  const int l15 = lane & 15, l16 = lane >> 4;

  const bf16* ga[2][2]; int la[2][2];
  const bf16* gb[2][2]; int lb[2][2];
  {
    int tr = tid >> 3, tc = tid & 7;
#pragma unroll
    for (int hh = 0; hh < 2; ++hh)
#pragma unroll
      for (int l = 0; l < 2; ++l) {
        int arow = hh * 64 + tr + l * 128;
        int asch = tc ^ (arow & 7);
        int ar = rt * 256 + arow; if (ar > ne - 1) ar = ne - 1;
        int tok = perm[pbase + ar];
        ga[hh][l] = xb + (size_t)tok * HIDDEN + asch * 8;
        la[hh][l] = arow * 64 + tc * 8;
        int rl = l * 64 + tr;
        int brow = hh * 32 + (rl & 31) + (rl >> 5) * 64;
        int bsch = tc ^ (brow & 7);
        int bn = ct * 256 + brow;
        gb[hh][l] = wb + ((size_t)e * INTER + bn) * HIDDEN + bsch * 8;
        lb[hh][l] = brow * 64 + tc * 8;
      }
  }

  f32x4 acc[8][4] = {};
  bf16x8 af[4][2];
  bf16x8 bfr[2][2][2];

  GEMM8_MAIN_LOOP(HIDDEN / 64)

  // ---- coalesced epilogue: gelu -> LDS (swizzled 256x256 bf16) -> bf16x8 stores ----
  float bias[4];
#pragma unroll
  for (int j4 = 0; j4 < 4; ++j4)
    bias[j4] = upb[e * INTER + ct * 256 + wc * 64 + j4 * 16 + l15];

  bf16* sT = &sMem[0][0];   // 256*256 bf16 = 128 KiB, main loop done
#pragma unroll
  for (int i8 = 0; i8 < 8; ++i8) {
#pragma unroll
    for (int tq = 0; tq < 4; ++tq) {
      int rr = wr * 128 + i8 * 16 + l16 * 4 + tq;
      int sw = ((rr >> 2) & 3) << 4;   // l16-dependent bank spread
#pragma unroll
      for (int j4 = 0; j4 < 4; ++j4) {
        int cc = wc * 64 + j4 * 16 + l15;
        float v = gelu_erf(acc[i8][j4][tq] + bias[j4]);
        sT[rr * 256 + (cc ^ sw)] = (bf16)v;
      }
    }
  }
  __syncthreads();
  {
    int halfq = lane >> 5;            // 0..1
    int ck = (lane & 31) * 8;         // col chunk base
#pragma unroll
    for (int it = 0; it < 16; ++it) {
      int rr = wid * 32 + it * 2 + halfq;
      int rg = rt * 256 + rr;
      if (rg < ne) {
        int sw = ((rr >> 2) & 3) << 4;
        bf16x8 val = *(const bf16x8*)&sT[rr * 256 + (ck ^ sw)];
        *(bf16x8*)&h[(size_t)(pbase + rg) * INTER + ct * 256 + ck] = val;
      }
    }
  }
}

// ---------------- 8-phase 256x256 grouped down GEMM (XCD-chunked, rt-inner) ----------------
#define DN_CT (HIDDEN / 256)  // 4
#define DN_RT 32
__global__ __launch_bounds__(512, 2)
void down_gemm8(const bf16* __restrict__ hh_, const bf16* __restrict__ wb,
                const float* __restrict__ dnb, const float* __restrict__ gates,
                const int* __restrict__ offs, float* __restrict__ y) {
  const int wgid = xcd_remap(blockIdx.x, DN_CT * DN_RT * NE);
  const int rt = wgid % DN_RT;
  const int ct = (wgid / DN_RT) % DN_CT;
  const int e  = wgid / (DN_CT * DN_RT);
  const int pbase = offs[e];
  const int ne = offs[e + 1] - pbase;
  if (rt * 256 >= ne) return;
  __shared__ __align__(16) bf16 sMem[4][256 * 64];
  bf16 (* const sA)[256 * 64] = sMem;
  bf16 (* const sB)[256 * 64] = sMem + 2;
  const int tid = threadIdx.x;
  const int lane = tid & 63;
  const int wid = tid >> 6;
  const int wr = wid >> 2;
  const int wc = wid & 3;
  const int l15 = lane & 15, l16 = lane >> 4;

  const bf16* ga[2][2]; int la[2][2];
  const bf16* gb[2][2]; int lb[2][2];
  {
    int tr = tid >> 3, tc = tid & 7;
#pragma unroll
    for (int hhp = 0; hhp < 2; ++hhp)
#pragma unroll
      for (int l = 0; l < 2; ++l) {
        int arow = hhp * 64 + tr + l * 128;
        int asch = tc ^ (arow & 7);
        int ar = rt * 256 + arow; if (ar > ne - 1) ar = ne - 1;
        ga[hhp][l] = hh_ + (size_t)(pbase + ar) * INTER + asch * 8;
        la[hhp][l] = arow * 64 + tc * 8;
        int rl = l * 64 + tr;
        int brow = hhp * 32 + (rl & 31) + (rl >> 5) * 64;
        int bsch = tc ^ (brow & 7);
        int bn = ct * 256 + brow;
        gb[hhp][l] = wb + ((size_t)e * HIDDEN + bn) * INTER + bsch * 8;
        lb[hhp][l] = brow * 64 + tc * 8;
      }
  }

  f32x4 acc[8][4] = {};
  bf16x8 af[4][2];
  bf16x8 bfr[2][2][2];

  GEMM8_MAIN_LOOP(INTER / 64)

  // epilogue: gate * (acc + bias), coalesced f32 stores
  float bias[4];
#pragma unroll
  for (int j4 = 0; j4 < 4; ++j4)
    bias[j4] = dnb[e * HIDDEN + ct * 256 + wc * 64 + j4 * 16 + l15];

#pragma unroll
  for (int i8 = 0; i8 < 8; ++i8) {
#pragma unroll
    for (int tq = 0; tq < 4; ++tq) {
      int r = rt * 256 + wr * 128 + i8 * 16 + l16 * 4 + tq;
      if (r < ne) {
        int slot = pbase + r;
        float gt = gates[slot];
#pragma unroll
        for (int j4 = 0; j4 < 4; ++j4) {
          int c = ct * 256 + wc * 64 + j4 * 16 + l15;
          y[(size_t)slot * HIDDEN + c] = gt * (acc[i8][j4][tq] + bias[j4]);
        }
      }
    }
  }
}

// ---------------- combine: out[t] = y[slot0] + y[slot1] ----------------
__global__ __launch_bounds__(256)
void combine_kernel(const float* __restrict__ y, const int* __restrict__ t2s,
                    float* __restrict__ out) {
  int t = blockIdx.x;
  int s0 = t2s[2 * t], s1 = t2s[2 * t + 1];
  const float4* a = (const float4*)(y + (size_t)s0 * HIDDEN);
  const float4* b = (const float4*)(y + (size_t)s1 * HIDDEN);
  float4* o = (float4*)(out + (size_t)t * HIDDEN);
  int c = threadIdx.x;
  float4 va = a[c], vb = b[c];
  o[c] = make_float4(va.x + vb.x, va.y + vb.y, va.z + vb.z, va.w + vb.w);
}

extern "C" void kernel_launch(void* const* d_in, const int* in_sizes, int n_in,
                              void* d_out, int out_size, void* d_ws, size_t ws_size,
                              hipStream_t stream) {
  const float* x   = (const float*)d_in[0];
  const float* lns = (const float*)d_in[1];
  const float* lnb = (const float*)d_in[2];
  const float* rw  = (const float*)d_in[3];
  const float* rb  = (const float*)d_in[4];
  const float* upw = (const float*)d_in[5];
  const float* upb = (const float*)d_in[6];
  const float* dww = (const float*)d_in[7];
  const float* dwb = (const float*)d_in[8];
  float* out = (float*)d_out;

  char* ws = (char*)d_ws;
  int* ctrl   = (int*)(ws + WS_CTRL);
  int* cnt    = ctrl;
  int* fill   = ctrl + 8;
  int* offs   = ctrl + 16;
  int* perm   = (int*)(ws + WS_PERM);
  float* gates = (float*)(ws + WS_GATES);
  int* eidx   = (int*)(ws + WS_EIDX);
  float* egate = (float*)(ws + WS_EGATE);
  bf16* xb    = (bf16*)(ws + WS_XB);
  bf16* upwb  = (bf16*)(ws + WS_UPWB);
  bf16* dwwb  = (bf16*)(ws + WS_DOWNWB);
  bf16* h     = (bf16*)(ws + WS_H);
  int* t2s    = (int*)(ws + WS_T2S);
  float* y    = (float*)(ws + WS_Y);

  const int T = in_sizes[0] / HIDDEN;  // 8192

  hipMemsetAsync(ctrl, 0, 256, stream);

  cvt_kernel<<<4096, 256, 0, stream>>>(upw, upwb, NE * INTER * HIDDEN / 4);
  cvt_kernel<<<4096, 256, 0, stream>>>(dww, dwwb, NE * HIDDEN * INTER / 4);
  router_kernel<<<T / 4, 256, 0, stream>>>(x, lns, lnb, rw, rb, xb, eidx, egate);
  hist_kernel<<<(2 * T) / 1024, 256, 0, stream>>>(eidx, cnt);
  scan_kernel<<<1, 64, 0, stream>>>(cnt, offs);
  scatter_kernel<<<(2 * T) / 1024, 256, 0, stream>>>(eidx, egate, offs, fill, perm, gates, t2s);

  up_gemm8<<<UP_CT * UP_RT * NE, 512, 0, stream>>>(xb, upwb, upb, perm, offs, h);
  down_gemm8<<<DN_CT * DN_RT * NE, 512, 0, stream>>>(h, dwwb, dwb, gates, offs, y);
  combine_kernel<<<T, 256, 0, stream>>>(y, t2s, out);
}

// Round 10
// 529.617 us; speedup vs baseline: 1.0835x; 1.0835x over previous
//
#include <hip/hip_runtime.h>
#include <math.h>

#define HIDDEN 1024
#define INTER 4096
#define NE 8

typedef __bf16 bf16;
typedef __bf16 bf16x8 __attribute__((ext_vector_type(8)));
typedef float f32x4 __attribute__((ext_vector_type(4)));

// ---- workspace layout (bytes) ----
#define WS_CTRL   ((size_t)0)
#define WS_PERM   ((size_t)256)
#define WS_GATES  ((size_t)65792)
#define WS_EIDX   ((size_t)131328)
#define WS_EGATE  ((size_t)196864)
#define WS_XB     ((size_t)262400)
#define WS_UPWB   ((size_t)17039616)
#define WS_DOWNWB ((size_t)84148480)
#define WS_H      ((size_t)151257344)
#define WS_T2S    ((size_t)285475072)
#define WS_Y      WS_UPWB   // y overlays upwb (dead after up_gemm)

__device__ __forceinline__ void async_copy16(const void* g, void* l) {
  __builtin_amdgcn_global_load_lds((const __attribute__((address_space(1))) void*)g,
                                   (__attribute__((address_space(3))) void*)l, 16, 0, 0);
}

// bijective XCD chunk remap (m204)
__device__ __forceinline__ int xcd_remap(int orig, int nwg) {
  int q = nwg >> 3, r = nwg & 7;
  int xcd = orig & 7, idx = orig >> 3;
  int base = (xcd < r) ? xcd * (q + 1) : r * (q + 1) + (xcd - r) * q;
  return base + idx;
}

// exact-erf GELU via Abramowitz-Stegun 7.1.26 (abs err 1.5e-7)
__device__ __forceinline__ float gelu_erf(float v) {
  float x = v * 0.70710678118654752440f;
  float ax = fabsf(x);
  float t = __builtin_amdgcn_rcpf(fmaf(0.3275911f, ax, 1.0f));
  float p = fmaf(t, 1.061405429f, -1.453152027f);
  p = fmaf(p, t, 1.421413741f);
  p = fmaf(p, t, -0.284496736f);
  p = fmaf(p, t, 0.254829592f);
  p = p * t;
  float e = __expf(-x * x);
  float er = 1.0f - p * e;
  er = copysignf(er, x);
  return 0.5f * v * (1.0f + er);
}

// ---------------- weight fp32 -> bf16 convert ----------------
__global__ void cvt_kernel(const float* __restrict__ w, bf16* __restrict__ wb, int n4) {
  int i = blockIdx.x * blockDim.x + threadIdx.x;
  int stride = gridDim.x * blockDim.x;
  for (; i < n4; i += stride) {
    float4 v = ((const float4*)w)[i];
    union { bf16 b[4]; uint2 u; } cv;
    cv.b[0] = (bf16)v.x; cv.b[1] = (bf16)v.y; cv.b[2] = (bf16)v.z; cv.b[3] = (bf16)v.w;
    ((uint2*)wb)[i] = cv.u;
  }
}

// ---------------- router: LN + logits + top2 + xb emit ----------------
__global__ __launch_bounds__(256)
void router_kernel(const float* __restrict__ x, const float* __restrict__ lns,
                   const float* __restrict__ lnb, const float* __restrict__ rw,
                   const float* __restrict__ rb, bf16* __restrict__ xb,
                   int* __restrict__ eidx, float* __restrict__ egate) {
  const int lane = threadIdx.x & 63;
  const int wid = threadIdx.x >> 6;
  const int t = blockIdx.x * 4 + wid;
  const float4* xr = (const float4*)(x + (size_t)t * HIDDEN);
  float4 v[4];
  float s = 0.f, ss = 0.f;
#pragma unroll
  for (int q = 0; q < 4; ++q) {
    v[q] = xr[q * 64 + lane];
    s += v[q].x + v[q].y + v[q].z + v[q].w;
    ss += v[q].x * v[q].x + v[q].y * v[q].y + v[q].z * v[q].z + v[q].w * v[q].w;
  }
#pragma unroll
  for (int o = 32; o; o >>= 1) { s += __shfl_xor(s, o, 64); ss += __shfl_xor(ss, o, 64); }
  const float mu = s * (1.f / HIDDEN);
  const float rstd = rsqrtf(ss * (1.f / HIDDEN) - mu * mu + 1e-5f);
  float acc[NE] = {};
#pragma unroll
  for (int q = 0; q < 4; ++q) {
    int i4 = q * 64 + lane;
    float4 xv = v[q];
    float4 sc = ((const float4*)lns)[i4];
    float4 bi = ((const float4*)lnb)[i4];
    float4 xn;
    xn.x = (xv.x - mu) * rstd * sc.x + bi.x;
    xn.y = (xv.y - mu) * rstd * sc.y + bi.y;
    xn.z = (xv.z - mu) * rstd * sc.z + bi.z;
    xn.w = (xv.w - mu) * rstd * sc.w + bi.w;
#pragma unroll
    for (int e2 = 0; e2 < NE; ++e2) {
      float4 w = ((const float4*)(rw + e2 * HIDDEN))[i4];
      acc[e2] += xn.x * w.x + xn.y * w.y + xn.z * w.z + xn.w * w.w;
    }
    union { bf16 b[4]; uint2 u; } cv;
    cv.b[0] = (bf16)xv.x; cv.b[1] = (bf16)xv.y; cv.b[2] = (bf16)xv.z; cv.b[3] = (bf16)xv.w;
    *(uint2*)&xb[(size_t)t * HIDDEN + i4 * 4] = cv.u;
  }
#pragma unroll
  for (int e2 = 0; e2 < NE; ++e2)
#pragma unroll
    for (int o = 32; o; o >>= 1) acc[e2] += __shfl_xor(acc[e2], o, 64);
  if (lane == 0) {
    float b0 = -1e30f, b1 = -1e30f; int i0 = 0, i1 = 0;
#pragma unroll
    for (int e2 = 0; e2 < NE; ++e2) {
      float lv = acc[e2] + rb[e2];
      if (lv > b0) { b1 = b0; i1 = i0; b0 = lv; i0 = e2; }
      else if (lv > b1) { b1 = lv; i1 = e2; }
    }
    float ex = expf(b1 - b0);
    float g0 = 1.f / (1.f + ex);
    float g1 = ex * g0;
    eidx[t * 2] = i0; eidx[t * 2 + 1] = i1;
    egate[t * 2] = g0; egate[t * 2 + 1] = g1;
  }
}

// ---------------- histogram ----------------
__global__ __launch_bounds__(256)
void hist_kernel(const int* __restrict__ eidx, int* __restrict__ cnt) {
  __shared__ int h8[NE];
  if (threadIdx.x < NE) h8[threadIdx.x] = 0;
  __syncthreads();
  int i = (blockIdx.x * 256 + threadIdx.x) * 4;
#pragma unroll
  for (int k = 0; k < 4; ++k) atomicAdd(&h8[eidx[i + k]], 1);
  __syncthreads();
  if (threadIdx.x < NE) atomicAdd(&cnt[threadIdx.x], h8[threadIdx.x]);
}

__global__ void scan_kernel(const int* cnt, int* offs) {
  if (threadIdx.x == 0 && blockIdx.x == 0) {
    int a = 0;
    for (int e = 0; e < NE; ++e) { offs[e] = a; a += cnt[e]; }
    offs[NE] = a;
  }
}

// ---------------- scatter ----------------
__global__ __launch_bounds__(256)
void scatter_kernel(const int* __restrict__ eidx, const float* __restrict__ egate,
                    const int* __restrict__ offs, int* __restrict__ fill,
                    int* __restrict__ perm, float* __restrict__ gates,
                    int* __restrict__ t2s) {
  __shared__ int h8[NE], base8[NE];
  if (threadIdx.x < NE) h8[threadIdx.x] = 0;
  __syncthreads();
  int i = (blockIdx.x * 256 + threadIdx.x) * 4;
  int ee[4], rk[4];
#pragma unroll
  for (int k = 0; k < 4; ++k) { ee[k] = eidx[i + k]; rk[k] = atomicAdd(&h8[ee[k]], 1); }
  __syncthreads();
  if (threadIdx.x < NE) base8[threadIdx.x] = atomicAdd(&fill[threadIdx.x], h8[threadIdx.x]);
  __syncthreads();
#pragma unroll
  for (int k = 0; k < 4; ++k) {
    int entry = i + k;
    int slot = offs[ee[k]] + base8[ee[k]] + rk[k];
    perm[slot] = entry >> 1;
    gates[slot] = egate[entry];
    t2s[entry] = slot;
  }
}

// ---------------- shared 8-phase 256x256 GEMM machinery ----------------
// Stage map (age-3 everywhere): {A0,B0}@P0, B1@P1, A1@P2, none@P3.
// Waits: VMW(6)@P0 retires B1(prev), VMW(6)@P1 retires A1(prev),
//        VMW(4)@P3 retires A0,B0(cur). Every READ's half retired >=1 phase
//        earlier with an intervening barrier (queue-simulated).
#define READ_A(hh, cb) { \
  _Pragma("unroll") for (int ii = 0; ii < 4; ++ii) \
  _Pragma("unroll") for (int ks = 0; ks < 2; ++ks) { \
    int r_ = wr * 128 + (hh) * 64 + ii * 16 + l15; \
    af[ii][ks] = *(const bf16x8*)&sA[cb][r_ * 64 + (((ks * 4 + l16) ^ (r_ & 7)) * 8)]; \
  } }

#define READ_B(jh, cb) { \
  _Pragma("unroll") for (int jj = 0; jj < 2; ++jj) \
  _Pragma("unroll") for (int ks = 0; ks < 2; ++ks) { \
    int n_ = wc * 64 + ((jh) * 2 + jj) * 16 + l15; \
    bfr[jh][jj][ks] = *(const bf16x8*)&sB[cb][n_ * 64 + (((ks * 4 + l16) ^ (n_ & 7)) * 8)]; \
  } }

#define STAGE_A(ha, nb) { \
  async_copy16(ga[ha][0], &sA[nb][la[ha][0]]); \
  async_copy16(ga[ha][1], &sA[nb][la[ha][1]]); \
  ga[ha][0] += 64; ga[ha][1] += 64; }

#define STAGE_B(hb, nb) { \
  async_copy16(gb[hb][0], &sB[nb][lb[hb][0]]); \
  async_copy16(gb[hb][1], &sB[nb][lb[hb][1]]); \
  gb[hb][0] += 64; gb[hb][1] += 64; }

#define MFMA_CLUSTER(I0, JH) \
  __builtin_amdgcn_s_barrier(); \
  asm volatile("s_waitcnt lgkmcnt(0)" ::: "memory"); \
  __builtin_amdgcn_sched_barrier(0); \
  __builtin_amdgcn_s_setprio(1); \
  { _Pragma("unroll") for (int ii = 0; ii < 4; ++ii) \
    _Pragma("unroll") for (int jj = 0; jj < 2; ++jj) \
    _Pragma("unroll") for (int ks = 0; ks < 2; ++ks) \
      acc[(I0) + ii][(JH) * 2 + jj] = __builtin_amdgcn_mfma_f32_16x16x32_bf16( \
          af[ii][ks], bfr[JH][jj][ks], acc[(I0) + ii][(JH) * 2 + jj], 0, 0, 0); } \
  __builtin_amdgcn_s_setprio(0); \
  __builtin_amdgcn_sched_barrier(0); \
  __builtin_amdgcn_s_barrier();

#define VMW(n) asm volatile("s_waitcnt vmcnt(" #n ")" ::: "memory");

#define GEMM8_MAIN_LOOP(NT) \
  STAGE_A(0, 0); STAGE_B(0, 0); STAGE_B(1, 0); STAGE_A(1, 0); \
  VMW(4); \
  __builtin_amdgcn_s_barrier(); \
  for (int t = 0; t < (NT) - 1; ++t) { \
    const int cb = t & 1, nb = cb ^ 1; \
    READ_A(0, cb); READ_B(0, cb); \
    STAGE_A(0, nb); STAGE_B(0, nb); \
    VMW(6); \
    MFMA_CLUSTER(0, 0); \
    READ_B(1, cb); \
    STAGE_B(1, nb); \
    VMW(6); \
    MFMA_CLUSTER(0, 1); \
    READ_A(1, cb); \
    STAGE_A(1, nb); \
    MFMA_CLUSTER(4, 1); \
    VMW(4); \
    MFMA_CLUSTER(4, 0); \
  } \
  { \
    const int cb = ((NT) - 1) & 1; \
    READ_A(0, cb); READ_B(0, cb); \
    VMW(0); \
    MFMA_CLUSTER(0, 0); \
    READ_B(1, cb); \
    MFMA_CLUSTER(0, 1); \
    READ_A(1, cb); \
    MFMA_CLUSTER(4, 1); \
    MFMA_CLUSTER(4, 0); \
  }

// ---------------- 8-phase 256x256 grouped up GEMM (XCD-chunked, ct-inner = R8) ----------------
#define UP_CT (INTER / 256)   // 16
#define UP_RT 32
__global__ __launch_bounds__(512, 2)
void up_gemm8(const bf16* __restrict__ xb, const bf16* __restrict__ wb,
              const float* __restrict__ upb, const int* __restrict__ perm,
              const int* __restrict__ offs, bf16* __restrict__ h) {
  const int wgid = xcd_remap(blockIdx.x, UP_CT * UP_RT * NE);
  const int ct = wgid % UP_CT;
  const int rt = (wgid / UP_CT) % UP_RT;
  const int e  = wgid / (UP_CT * UP_RT);
  const int pbase = offs[e];
  const int ne = offs[e + 1] - pbase;
  if (rt * 256 >= ne) return;
  __shared__ __align__(16) bf16 sMem[4][256 * 64];   // sA = [0..1], sB = [2..3]
  bf16 (* const sA)[256 * 64] = sMem;
  bf16 (* const sB)[256 * 64] = sMem + 2;
  const int tid = threadIdx.x;
  const int lane = tid & 63;
  const int wid = tid >> 6;
  const int wr = wid >> 2;
  const int wc = wid & 3;
  const int l15 = lane & 15, l16 = lane >> 4;

  const bf16* ga[2][2]; int la[2][2];
  const bf16* gb[2][2]; int lb[2][2];
  {
    int tr = tid >> 3, tc = tid & 7;
#pragma unroll
    for (int hh = 0; hh < 2; ++hh)
#pragma unroll
      for (int l = 0; l < 2; ++l) {
        int arow = hh * 64 + tr + l * 128;
        int asch = tc ^ (arow & 7);
        int ar = rt * 256 + arow; if (ar > ne - 1) ar = ne - 1;
        int tok = perm[pbase + ar];
        ga[hh][l] = xb + (size_t)tok * HIDDEN + asch * 8;
        la[hh][l] = arow * 64 + tc * 8;
        int rl = l * 64 + tr;
        int brow = hh * 32 + (rl & 31) + (rl >> 5) * 64;
        int bsch = tc ^ (brow & 7);
        int bn = ct * 256 + brow;
        gb[hh][l] = wb + ((size_t)e * INTER + bn) * HIDDEN + bsch * 8;
        lb[hh][l] = brow * 64 + tc * 8;
      }
  }

  f32x4 acc[8][4] = {};
  bf16x8 af[4][2];
  bf16x8 bfr[2][2][2];

  GEMM8_MAIN_LOOP(HIDDEN / 64)

  // ---- coalesced epilogue: gelu -> LDS (swizzled 256x256 bf16) -> bf16x8 stores ----
  float bias[4];
#pragma unroll
  for (int j4 = 0; j4 < 4; ++j4)
    bias[j4] = upb[e * INTER + ct * 256 + wc * 64 + j4 * 16 + l15];

  bf16* sT = &sMem[0][0];   // 256*256 bf16 = 128 KiB, main loop done
#pragma unroll
  for (int i8 = 0; i8 < 8; ++i8) {
#pragma unroll
    for (int tq = 0; tq < 4; ++tq) {
      int rr = wr * 128 + i8 * 16 + l16 * 4 + tq;
      int sw = ((rr >> 2) & 3) << 4;   // l16-dependent bank spread
#pragma unroll
      for (int j4 = 0; j4 < 4; ++j4) {
        int cc = wc * 64 + j4 * 16 + l15;
        float v = gelu_erf(acc[i8][j4][tq] + bias[j4]);
        sT[rr * 256 + (cc ^ sw)] = (bf16)v;
      }
    }
  }
  __syncthreads();
  {
    int halfq = lane >> 5;            // 0..1
    int ck = (lane & 31) * 8;         // col chunk base
#pragma unroll
    for (int it = 0; it < 16; ++it) {
      int rr = wid * 32 + it * 2 + halfq;
      int rg = rt * 256 + rr;
      if (rg < ne) {
        int sw = ((rr >> 2) & 3) << 4;
        bf16x8 val = *(const bf16x8*)&sT[rr * 256 + (ck ^ sw)];
        *(bf16x8*)&h[(size_t)(pbase + rg) * INTER + ct * 256 + ck] = val;
      }
    }
  }
}

// ---------------- 8-phase 256x256 grouped down GEMM (XCD-chunked, ct-inner = R8) ----------------
#define DN_CT (HIDDEN / 256)  // 4
#define DN_RT 32
__global__ __launch_bounds__(512, 2)
void down_gemm8(const bf16* __restrict__ hh_, const bf16* __restrict__ wb,
                const float* __restrict__ dnb, const float* __restrict__ gates,
                const int* __restrict__ offs, float* __restrict__ y) {
  const int wgid = xcd_remap(blockIdx.x, DN_CT * DN_RT * NE);
  const int ct = wgid % DN_CT;
  const int rt = (wgid / DN_CT) % DN_RT;
  const int e  = wgid / (DN_CT * DN_RT);
  const int pbase = offs[e];
  const int ne = offs[e + 1] - pbase;
  if (rt * 256 >= ne) return;
  __shared__ __align__(16) bf16 sMem[4][256 * 64];
  bf16 (* const sA)[256 * 64] = sMem;
  bf16 (* const sB)[256 * 64] = sMem + 2;
  const int tid = threadIdx.x;
  const int lane = tid & 63;
  const int wid = tid >> 6;
  const int wr = wid >> 2;
  const int wc = wid & 3;
  const int l15 = lane & 15, l16 = lane >> 4;

  const bf16* ga[2][2]; int la[2][2];
  const bf16* gb[2][2]; int lb[2][2];
  {
    int tr = tid >> 3, tc = tid & 7;
#pragma unroll
    for (int hhp = 0; hhp < 2; ++hhp)
#pragma unroll
      for (int l = 0; l < 2; ++l) {
        int arow = hhp * 64 + tr + l * 128;
        int asch = tc ^ (arow & 7);
        int ar = rt * 256 + arow; if (ar > ne - 1) ar = ne - 1;
        ga[hhp][l] = hh_ + (size_t)(pbase + ar) * INTER + asch * 8;
        la[hhp][l] = arow * 64 + tc * 8;
        int rl = l * 64 + tr;
        int brow = hhp * 32 + (rl & 31) + (rl >> 5) * 64;
        int bsch = tc ^ (brow & 7);
        int bn = ct * 256 + brow;
        gb[hhp][l] = wb + ((size_t)e * HIDDEN + bn) * INTER + bsch * 8;
        lb[hhp][l] = brow * 64 + tc * 8;
      }
  }

  f32x4 acc[8][4] = {};
  bf16x8 af[4][2];
  bf16x8 bfr[2][2][2];

  GEMM8_MAIN_LOOP(INTER / 64)

  // epilogue: gate * (acc + bias), coalesced f32 stores
  float bias[4];
#pragma unroll
  for (int j4 = 0; j4 < 4; ++j4)
    bias[j4] = dnb[e * HIDDEN + ct * 256 + wc * 64 + j4 * 16 + l15];

#pragma unroll
  for (int i8 = 0; i8 < 8; ++i8) {
#pragma unroll
    for (int tq = 0; tq < 4; ++tq) {
      int r = rt * 256 + wr * 128 + i8 * 16 + l16 * 4 + tq;
      if (r < ne) {
        int slot = pbase + r;
        float gt = gates[slot];
#pragma unroll
        for (int j4 = 0; j4 < 4; ++j4) {
          int c = ct * 256 + wc * 64 + j4 * 16 + l15;
          y[(size_t)slot * HIDDEN + c] = gt * (acc[i8][j4][tq] + bias[j4]);
        }
      }
    }
  }
}

// ---------------- combine: out[t] = y[slot0] + y[slot1] ----------------
__global__ __launch_bounds__(256)
void combine_kernel(const float* __restrict__ y, const int* __restrict__ t2s,
                    float* __restrict__ out) {
  int t = blockIdx.x;
  int s0 = t2s[2 * t], s1 = t2s[2 * t + 1];
  const float4* a = (const float4*)(y + (size_t)s0 * HIDDEN);
  const float4* b = (const float4*)(y + (size_t)s1 * HIDDEN);
  float4* o = (float4*)(out + (size_t)t * HIDDEN);
  int c = threadIdx.x;
  float4 va = a[c], vb = b[c];
  o[c] = make_float4(va.x + vb.x, va.y + vb.y, va.z + vb.z, va.w + vb.w);
}

extern "C" void kernel_launch(void* const* d_in, const int* in_sizes, int n_in,
                              void* d_out, int out_size, void* d_ws, size_t ws_size,
                              hipStream_t stream) {
  const float* x   = (const float*)d_in[0];
  const float* lns = (const float*)d_in[1];
  const float* lnb = (const float*)d_in[2];
  const float* rw  = (const float*)d_in[3];
  const float* rb  = (const float*)d_in[4];
  const float* upw = (const float*)d_in[5];
  const float* upb = (const float*)d_in[6];
  const float* dww = (const float*)d_in[7];
  const float* dwb = (const float*)d_in[8];
  float* out = (float*)d_out;

  char* ws = (char*)d_ws;
  int* ctrl   = (int*)(ws + WS_CTRL);
  int* cnt    = ctrl;
  int* fill   = ctrl + 8;
  int* offs   = ctrl + 16;
  int* perm   = (int*)(ws + WS_PERM);
  float* gates = (float*)(ws + WS_GATES);
  int* eidx   = (int*)(ws + WS_EIDX);
  float* egate = (float*)(ws + WS_EGATE);
  bf16* xb    = (bf16*)(ws + WS_XB);
  bf16* upwb  = (bf16*)(ws + WS_UPWB);
  bf16* dwwb  = (bf16*)(ws + WS_DOWNWB);
  bf16* h     = (bf16*)(ws + WS_H);
  int* t2s    = (int*)(ws + WS_T2S);
  float* y    = (float*)(ws + WS_Y);

  const int T = in_sizes[0] / HIDDEN;  // 8192

  hipMemsetAsync(ctrl, 0, 256, stream);

  cvt_kernel<<<4096, 256, 0, stream>>>(upw, upwb, NE * INTER * HIDDEN / 4);
  cvt_kernel<<<4096, 256, 0, stream>>>(dww, dwwb, NE * HIDDEN * INTER / 4);
  router_kernel<<<T / 4, 256, 0, stream>>>(x, lns, lnb, rw, rb, xb, eidx, egate);
  hist_kernel<<<(2 * T) / 1024, 256, 0, stream>>>(eidx, cnt);
  scan_kernel<<<1, 64, 0, stream>>>(cnt, offs);
  scatter_kernel<<<(2 * T) / 1024, 256, 0, stream>>>(eidx, egate, offs, fill, perm, gates, t2s);

  up_gemm8<<<UP_CT * UP_RT * NE, 512, 0, stream>>>(xb, upwb, upb, perm, offs, h);
  down_gemm8<<<DN_CT * DN_RT * NE, 512, 0, stream>>>(h, dwwb, dwb, gates, offs, y);
  combine_kernel<<<T, 256, 0, stream>>>(y, t2s, out);
}